// Round 13
// baseline (7386.131 us; speedup 1.0000x reference)
//
#include <hip/hip_runtime.h>
#include <hip/hip_cooperative_groups.h>

namespace cg = cooperative_groups;

typedef unsigned short u16;
constexpr int Ss = 128, Hn = 1024, En = 512, Cn = 512, Vn = 32000;
constexpr size_t PL = 1024u * 1024u;

using short8 = __attribute__((ext_vector_type(8))) short;
using f32x4  = __attribute__((ext_vector_type(4))) float;

// ---- static device scratch (all planes rewritten in-launch before read) ----
__device__ __align__(1024) u16 g_hh[2][PL];   // h ping-pong, hi
__device__ __align__(1024) u16 g_hl[2][PL];   // h ping-pong, lo
__device__ __align__(1024) u16 g_yh[PL], g_yl[PL];
__device__ __align__(1024) u16 g_zh[PL], g_zl[PL];
__device__ __align__(1024) float g_proj[(size_t)Vn * Hn];  // emb@Wih^T + bih + bhh
// bf16 hi/lo split tables (recomputed every launch; deterministic)
__device__ __align__(1024) u16 t_eh[(size_t)Vn * En], t_el[(size_t)Vn * En];
__device__ __align__(1024) u16 t_xh[(size_t)Hn * En], t_xl[(size_t)Hn * En];  // Wih
__device__ __align__(1024) u16 t_hh[(size_t)Hn * Hn], t_hl[(size_t)Hn * Hn];  // Whh
__device__ __align__(1024) u16 t_1h[(size_t)Hn * Hn], t_1l[(size_t)Hn * Hn];  // W1
__device__ __align__(1024) u16 t_2h[(size_t)Cn * Hn], t_2l[(size_t)Cn * Hn];  // W2

__device__ __forceinline__ void gl16(const void* g, void* l) {
  __builtin_amdgcn_global_load_lds((const __attribute__((address_space(1))) void*)g,
                                   (__attribute__((address_space(3))) void*)l, 16, 0, 0);
}
__device__ __forceinline__ unsigned f2bf(float f) {
  unsigned u = __float_as_uint(f);
  return (u + 0x7fffu + ((u >> 16) & 1u)) >> 16;
}
__device__ __forceinline__ float bf2f(unsigned u) { return __uint_as_float(u << 16); }

__global__ void cvt_split(const float* __restrict__ src, int which, int n) {
  u16 *hi, *lo;
  switch (which) {
    case 0: hi = t_eh; lo = t_el; break;
    case 1: hi = t_xh; lo = t_xl; break;
    case 2: hi = t_hh; lo = t_hl; break;
    case 3: hi = t_1h; lo = t_1l; break;
    default: hi = t_2h; lo = t_2l; break;
  }
  for (int i = blockIdx.x * blockDim.x + threadIdx.x; i < n; i += gridDim.x * blockDim.x) {
    const float v = src[i];
    const unsigned h = f2bf(v);
    hi[i] = (u16)h;
    lo[i] = (u16)f2bf(v - bf2f(h));
  }
}

// Shared GEMM-tile prolog (r12-proven: 64x64 tile, 8 waves 4x2, m89 frags).
#define GEMM_PROLOG()                                                          \
  const int tid = threadIdx.x, bid = blockIdx.x;                               \
  const int w = tid >> 6, l = tid & 63;                                        \
  const int wr = w & 3, wc = w >> 2;                                           \
  const int lrow = l & 15, lk = l >> 4;                                        \
  const int sr = tid >> 3, p = tid & 7;                                        \
  const int sby = ((p ^ (sr & 7)) << 4);                                       \
  const int arow = (wr << 4) + lrow;                                           \
  int aoff[2], bboff[2][2];                                                    \
  _Pragma("unroll") for (int s = 0; s < 2; ++s)                                \
      aoff[s] = arow * 128 + ((s * 64 + lk * 16) ^ ((arow & 7) << 4));         \
  _Pragma("unroll") for (int n = 0; n < 2; ++n) {                              \
    const int jl = (wc << 5) + (n << 4) + lrow;                                \
    _Pragma("unroll") for (int s = 0; s < 2; ++s)                              \
        bboff[n][s] = jl * 128 + ((s * 64 + lk * 16) ^ ((jl & 7) << 4));       \
  }

#define GEMM_MFMA(ca, cb)                                                      \
  _Pragma("unroll") for (int s = 0; s < 2; ++s) {                              \
    short8 a = *(const short8*)((ca) + aoff[s]);                               \
    _Pragma("unroll") for (int n = 0; n < 2; ++n) {                            \
      short8 b = *(const short8*)((cb) + bboff[n][s]);                         \
      acc[n] = __builtin_amdgcn_mfma_f32_16x16x32_bf16(a, b, acc[n], 0, 0, 0); \
    }                                                                          \
  }

// proj[v][j] = emb[v] @ Wih^T + bih[j] + bhh[j]   (unchanged from r12, green)
__global__ void __launch_bounds__(512) proj_k(const float* __restrict__ bih,
                                              const float* __restrict__ bhh) {
  __shared__ char sA[16384];
  __shared__ char sB[16384];
  GEMM_PROLOG()
  const int j0 = (bid & 15) << 6;
  const int v0 = (bid >> 4) << 6;

  f32x4 acc[2];
#pragma unroll
  for (int n = 0; n < 2; ++n) {
    const float bs = bih[j0 + (wc << 5) + (n << 4) + lrow] +
                     bhh[j0 + (wc << 5) + (n << 4) + lrow];
#pragma unroll
    for (int ri = 0; ri < 4; ++ri) acc[n][ri] = bs;
  }

  auto stage = [&](int c) {
    char* da = sA + (c & 1) * 8192;
    char* db = sB + (c & 1) * 8192;
    const u16* ap = (c >= 8 && c < 16) ? t_el : t_eh;
    const u16* bp = (c < 16) ? t_xh : t_xl;
    const int kb = (c & 7) * 128;
    gl16((const char*)ap + (size_t)(v0 + sr) * 1024 + kb + sby, da + w * 1024);
    gl16((const char*)bp + (size_t)(j0 + sr) * 1024 + kb + sby, db + w * 1024);
  };
  stage(0);
  __syncthreads();
  for (int c = 0; c < 24; ++c) {
    const char* ca = sA + (c & 1) * 8192;
    const char* cb = sB + (c & 1) * 8192;
    if (c < 23) stage(c + 1);
    GEMM_MFMA(ca, cb)
    __syncthreads();
  }
#pragma unroll
  for (int n = 0; n < 2; ++n) {
    const int j = j0 + (wc << 5) + (n << 4) + lrow;
#pragma unroll
    for (int ri = 0; ri < 4; ++ri)
      g_proj[(size_t)(v0 + (wr << 4) + lk * 4 + ri) * 1024 + j] = acc[n][ri];
  }
}

// Persistent RNN scan. W_hh-hi resident in LDS (128 KB) for all 128 steps.
// Per step: 64 ring chunks (k=32): c<32 stage {A_hi|A_lo} -> A_hi@W_hi + A_lo@W_hi;
// c>=32 stage {A_hi|W_lo} -> A_hi@W_lo. Ring-3, counted vmcnt(2), raw barriers.
__global__ void __launch_bounds__(512) rnn_scan(const int* __restrict__ x_in,
                                                const int* __restrict__ x_len) {
  cg::grid_group grid = cg::this_grid();
  extern __shared__ char smem[];
  char* Wp   = smem;            // 131072 B: W_hh hi [16 q][64 j][128 B], XOR-swizzled
  char* ring = smem + 131072;   // 3 x 8192 B slots: {half0 4K | half1 4K}, 64-B rows

  const int tid = threadIdx.x, bid = blockIdx.x;
  const int w = tid >> 6, l = tid & 63;
  const int wr = w & 3, wc = w >> 2;
  const int lrow = l & 15, lk = l >> 4;
  const int b0 = (bid & 15) << 6, j0 = (bid >> 4) << 6;
  // W_hi staging geometry (128-B rows; r12-proven)
  const int sr = tid >> 3, p = tid & 7;
  const int sbyW = ((p ^ (sr & 7)) << 4);
  // ring staging geometry (64-B rows, (row>>1)&3 XOR -> 2-way banks)
  const int rr = (tid >> 2) & 63, p2 = tid & 3;
  const int sbyR = ((p2 ^ ((rr >> 1) & 3)) << 4);
  const int arow = (wr << 4) + lrow;

  // fragment offsets
  const int aoffH = arow * 64 + ((lk * 16) ^ (((arow >> 1) & 3) << 4)); // half0
  int jb[2], xs[2], wofL[2], jcol[2];
#pragma unroll
  for (int n = 0; n < 2; ++n) {
    const int jl = (wc << 5) + (n << 4) + lrow;
    jb[n] = jl * 128;
    xs[n] = (jl & 7) << 4;
    wofL[n] = 4096 + jl * 64 + ((lk * 16) ^ (((jl >> 1) & 3) << 4));    // half1 W_lo
    jcol[n] = j0 + jl;
  }
  int lenv[4];
#pragma unroll
  for (int ri = 0; ri < 4; ++ri) lenv[ri] = x_len[b0 + (wr << 4) + lk * 4 + ri];

  // stage persistent W_hh-hi once: 16 rounds x 8 KB
#pragma unroll
  for (int q = 0; q < 16; ++q)
    gl16((const char*)t_hh + (size_t)(j0 + sr) * 2048 + q * 128 + sbyW,
         Wp + q * 8192 + w * 1024);
  __syncthreads();

  for (int t = 0; t < Ss; ++t) {
    const u16* hinh = g_hh[t & 1];
    const u16* hinl = g_hl[t & 1];
    u16* houth = g_hh[(t + 1) & 1];
    u16* houtl = g_hl[(t + 1) & 1];

    // token + x-projection gather (issued first; consumed in tail)
    int tok[4];
#pragma unroll
    for (int ri = 0; ri < 4; ++ri)
      tok[ri] = x_in[(b0 + (wr << 4) + lk * 4 + ri) * Ss + t];
    float pj[2][4];
#pragma unroll
    for (int n = 0; n < 2; ++n)
#pragma unroll
      for (int ri = 0; ri < 4; ++ri)
        pj[n][ri] = g_proj[(size_t)tok[ri] * 1024 + jcol[n]];
    asm volatile("" ::: "memory");   // keep pj loads ordered before ring issues

    f32x4 acc[2];
    acc[0] = (f32x4){0.f, 0.f, 0.f, 0.f}; acc[1] = acc[0];

    if (t > 0) {
      auto issue = [&](int cc, int slotb) {
        const int kb = (cc < 32 ? cc : cc - 32) * 64;
        const u16* src;
        size_t rowb;
        if (w < 4)            { src = hinh; rowb = (size_t)(b0 + rr) * 2048; }
        else if (cc < 32)     { src = hinl; rowb = (size_t)(b0 + rr) * 2048; }
        else                  { src = t_hl; rowb = (size_t)(j0 + rr) * 2048; }
        gl16((const char*)src + rowb + kb + sbyR, ring + slotb + w * 1024);
      };
      issue(0, 0); issue(1, 8192); issue(2, 16384);
      int slotb = 0;
      for (int c = 0; c < 64; ++c) {
        if (c < 62)      asm volatile("s_waitcnt vmcnt(2)" ::: "memory");
        else if (c == 62) asm volatile("s_waitcnt vmcnt(1)" ::: "memory");
        else             asm volatile("s_waitcnt vmcnt(0)" ::: "memory");
        __builtin_amdgcn_s_barrier();
        __builtin_amdgcn_sched_barrier(0);
        const char* sl = ring + slotb;
        if (c < 32) {
          const int q = c >> 1, k64 = (c & 1) * 64;
          short8 aH = *(const short8*)(sl + aoffH);
          short8 aL = *(const short8*)(sl + aoffH + 4096);
#pragma unroll
          for (int n = 0; n < 2; ++n) {
            short8 b = *(const short8*)(Wp + q * 8192 + jb[n] + ((k64 + lk * 16) ^ xs[n]));
            acc[n] = __builtin_amdgcn_mfma_f32_16x16x32_bf16(aH, b, acc[n], 0, 0, 0);
            acc[n] = __builtin_amdgcn_mfma_f32_16x16x32_bf16(aL, b, acc[n], 0, 0, 0);
          }
        } else {
          short8 aH = *(const short8*)(sl + aoffH);
#pragma unroll
          for (int n = 0; n < 2; ++n) {
            short8 b = *(const short8*)(sl + wofL[n]);
            acc[n] = __builtin_amdgcn_mfma_f32_16x16x32_bf16(aH, b, acc[n], 0, 0, 0);
          }
        }
        __builtin_amdgcn_s_barrier();
        if (c + 3 < 64) issue(c + 3, slotb);
        slotb = (slotb == 16384) ? 0 : slotb + 8192;
      }
    }

    // tail: tanh, split-store h, y-capture
#pragma unroll
    for (int n = 0; n < 2; ++n) {
#pragma unroll
      for (int ri = 0; ri < 4; ++ri) {
        const int brow = b0 + (wr << 4) + lk * 4 + ri;
        const float v = tanhf(acc[n][ri] + pj[n][ri]);
        const unsigned hi = f2bf(v);
        const unsigned lo = f2bf(v - bf2f(hi));
        const size_t off = (size_t)brow * 1024 + jcol[n];
        houth[off] = (u16)hi;
        houtl[off] = (u16)lo;
        if (lenv[ri] == t + 1) { g_yh[off] = (u16)hi; g_yl[off] = (u16)lo; }
      }
    }
    grid.sync();
  }
}

// MLP (unchanged from r12, green)
__global__ void __launch_bounds__(512) mlp_k(const float* __restrict__ bias,
                                             float* __restrict__ out, int mode) {
  __shared__ char sA[16384];
  __shared__ char sB[16384];
  GEMM_PROLOG()
  const int b0 = (bid & 15) << 6, j0 = (bid >> 4) << 6;
  const u16* ah = mode ? g_zh : g_yh;
  const u16* al = mode ? g_zl : g_yl;
  const u16* bh = mode ? t_2h : t_1h;
  const u16* bl = mode ? t_2l : t_1l;

  f32x4 acc[2];
#pragma unroll
  for (int n = 0; n < 2; ++n) {
    const float bs = bias[j0 + (wc << 5) + (n << 4) + lrow];
#pragma unroll
    for (int ri = 0; ri < 4; ++ri) acc[n][ri] = bs;
  }

  auto stage = [&](int c) {
    char* da = sA + (c & 1) * 8192;
    char* db = sB + (c & 1) * 8192;
    const u16* ap = (c >= 16 && c < 32) ? al : ah;
    const u16* bp = (c < 32) ? bh : bl;
    const int kb = (c & 15) * 128;
    gl16((const char*)ap + (size_t)(b0 + sr) * 2048 + kb + sby, da + w * 1024);
    gl16((const char*)bp + (size_t)(j0 + sr) * 2048 + kb + sby, db + w * 1024);
  };
  stage(0);
  __syncthreads();
  for (int c = 0; c < 48; ++c) {
    const char* ca = sA + (c & 1) * 8192;
    const char* cb = sB + (c & 1) * 8192;
    if (c < 47) stage(c + 1);
    GEMM_MFMA(ca, cb)
    __syncthreads();
  }

#pragma unroll
  for (int n = 0; n < 2; ++n) {
    const int j = j0 + (wc << 5) + (n << 4) + lrow;
#pragma unroll
    for (int ri = 0; ri < 4; ++ri) {
      const int brow = b0 + (wr << 4) + lk * 4 + ri;
      if (mode == 0) {
        const float v = fmaxf(acc[n][ri], 0.f);
        const unsigned hi = f2bf(v);
        const unsigned lo = f2bf(v - bf2f(hi));
        const size_t off = (size_t)brow * 1024 + j;
        g_zh[off] = (u16)hi;
        g_zl[off] = (u16)lo;
      } else {
        out[(size_t)brow * 512 + j] = acc[n][ri];
      }
    }
  }
}

extern "C" void kernel_launch(void* const* d_in, const int* in_sizes, int n_in,
                              void* d_out, int out_size, void* d_ws, size_t ws_size,
                              hipStream_t stream) {
  const int*   x_in  = (const int*)d_in[0];
  const int*   x_len = (const int*)d_in[1];
  const float* emb = (const float*)d_in[2];
  const float* Wih = (const float*)d_in[3];
  const float* Whh = (const float*)d_in[4];
  const float* bih = (const float*)d_in[5];
  const float* bhh = (const float*)d_in[6];
  const float* W1  = (const float*)d_in[7];
  const float* b1  = (const float*)d_in[8];
  const float* W2  = (const float*)d_in[9];
  const float* b2  = (const float*)d_in[10];
  float* out = (float*)d_out;

  (void)hipFuncSetAttribute((const void*)rnn_scan,
                            hipFuncAttributeMaxDynamicSharedMemorySize, 155648);

  cvt_split<<<dim3(4096), dim3(256), 0, stream>>>(emb, 0, Vn * En);
  cvt_split<<<dim3(1024), dim3(256), 0, stream>>>(Wih, 1, Hn * En);
  cvt_split<<<dim3(2048), dim3(256), 0, stream>>>(Whh, 2, Hn * Hn);
  cvt_split<<<dim3(2048), dim3(256), 0, stream>>>(W1, 3, Hn * Hn);
  cvt_split<<<dim3(1024), dim3(256), 0, stream>>>(W2, 4, Cn * Hn);

  proj_k<<<dim3(8000), dim3(512), 0, stream>>>(bih, bhh);

  void* args[] = {(void*)&x_in, (void*)&x_len};
  (void)hipLaunchCooperativeKernel((const void*)rnn_scan, dim3(256), dim3(512),
                                   args, 155648, stream);

  mlp_k<<<dim3(256), dim3(512), 0, stream>>>(b1, nullptr, 0);
  mlp_k<<<dim3(128), dim3(512), 0, stream>>>(b2, out, 1);
}

// Round 14
// 1992.222 us; speedup vs baseline: 3.7075x; 3.7075x over previous
//
#include <hip/hip_runtime.h>

typedef unsigned short u16;
constexpr int Ss = 128, Hn = 1024, En = 512, Cn = 512, Vn = 32000;
constexpr size_t PL = 1024u * 1024u;

using short8 = __attribute__((ext_vector_type(8))) short;
using f32x4  = __attribute__((ext_vector_type(4))) float;

// ---- static device scratch (all planes rewritten in-launch before read) ----
__device__ __align__(1024) u16 g_hh[2][PL];   // h ping-pong, hi
__device__ __align__(1024) u16 g_hl[2][PL];   // h ping-pong, lo
__device__ __align__(1024) u16 g_yh[PL], g_yl[PL];
__device__ __align__(1024) u16 g_zh[PL], g_zl[PL];
__device__ __align__(1024) float g_proj[(size_t)Vn * Hn];  // emb@Wih^T + bih + bhh
// bf16 hi/lo split tables (recomputed every launch; deterministic)
__device__ __align__(1024) u16 t_eh[(size_t)Vn * En], t_el[(size_t)Vn * En];
__device__ __align__(1024) u16 t_xh[(size_t)Hn * En], t_xl[(size_t)Hn * En];  // Wih
__device__ __align__(1024) u16 t_hh[(size_t)Hn * Hn], t_hl[(size_t)Hn * Hn];  // Whh
__device__ __align__(1024) u16 t_1h[(size_t)Hn * Hn], t_1l[(size_t)Hn * Hn];  // W1
__device__ __align__(1024) u16 t_2h[(size_t)Cn * Hn], t_2l[(size_t)Cn * Hn];  // W2

__device__ __forceinline__ void gl16(const void* g, void* l) {
  __builtin_amdgcn_global_load_lds((const __attribute__((address_space(1))) void*)g,
                                   (__attribute__((address_space(3))) void*)l, 16, 0, 0);
}
__device__ __forceinline__ unsigned f2bf(float f) {
  unsigned u = __float_as_uint(f);
  return (u + 0x7fffu + ((u >> 16) & 1u)) >> 16;
}
__device__ __forceinline__ float bf2f(unsigned u) { return __uint_as_float(u << 16); }

__global__ void cvt_split(const float* __restrict__ src, int which, int n) {
  u16 *hi, *lo;
  switch (which) {
    case 0: hi = t_eh; lo = t_el; break;
    case 1: hi = t_xh; lo = t_xl; break;
    case 2: hi = t_hh; lo = t_hl; break;
    case 3: hi = t_1h; lo = t_1l; break;
    default: hi = t_2h; lo = t_2l; break;
  }
  for (int i = blockIdx.x * blockDim.x + threadIdx.x; i < n; i += gridDim.x * blockDim.x) {
    const float v = src[i];
    const unsigned h = f2bf(v);
    hi[i] = (u16)h;
    lo[i] = (u16)f2bf(v - bf2f(h));
  }
}

// Shared GEMM-tile prolog (r12-proven: 64x64 tile, 8 waves 4x2, m89 frags,
// XOR-swizzled LDS via gl16).
#define GEMM_PROLOG()                                                          \
  const int tid = threadIdx.x, bid = blockIdx.x;                               \
  const int w = tid >> 6, l = tid & 63;                                        \
  const int wr = w & 3, wc = w >> 2;                                           \
  const int lrow = l & 15, lk = l >> 4;                                        \
  const int sr = tid >> 3, p = tid & 7;                                        \
  const int sby = ((p ^ (sr & 7)) << 4);                                       \
  const int arow = (wr << 4) + lrow;                                           \
  int aoff[2], bboff[2][2];                                                    \
  _Pragma("unroll") for (int s = 0; s < 2; ++s)                                \
      aoff[s] = arow * 128 + ((s * 64 + lk * 16) ^ ((arow & 7) << 4));         \
  _Pragma("unroll") for (int n = 0; n < 2; ++n) {                              \
    const int jl = (wc << 5) + (n << 4) + lrow;                                \
    _Pragma("unroll") for (int s = 0; s < 2; ++s)                              \
        bboff[n][s] = jl * 128 + ((s * 64 + lk * 16) ^ ((jl & 7) << 4));       \
  }

#define GEMM_MFMA(ca, cb)                                                      \
  _Pragma("unroll") for (int s = 0; s < 2; ++s) {                              \
    short8 a = *(const short8*)((ca) + aoff[s]);                               \
    _Pragma("unroll") for (int n = 0; n < 2; ++n) {                            \
      short8 b = *(const short8*)((cb) + bboff[n][s]);                         \
      acc[n] = __builtin_amdgcn_mfma_f32_16x16x32_bf16(a, b, acc[n], 0, 0, 0); \
    }                                                                          \
  }

// proj[v][j] = emb[v] @ Wih^T + bih[j] + bhh[j]   (unchanged from r12, green)
__global__ void __launch_bounds__(512) proj_k(const float* __restrict__ bih,
                                              const float* __restrict__ bhh) {
  __shared__ char sA[16384];
  __shared__ char sB[16384];
  GEMM_PROLOG()
  const int j0 = (bid & 15) << 6;
  const int v0 = (bid >> 4) << 6;

  f32x4 acc[2];
#pragma unroll
  for (int n = 0; n < 2; ++n) {
    const float bs = bih[j0 + (wc << 5) + (n << 4) + lrow] +
                     bhh[j0 + (wc << 5) + (n << 4) + lrow];
#pragma unroll
    for (int ri = 0; ri < 4; ++ri) acc[n][ri] = bs;
  }

  auto stage = [&](int c) {
    char* da = sA + (c & 1) * 8192;
    char* db = sB + (c & 1) * 8192;
    const u16* ap = (c >= 8 && c < 16) ? t_el : t_eh;
    const u16* bp = (c < 16) ? t_xh : t_xl;
    const int kb = (c & 7) * 128;
    gl16((const char*)ap + (size_t)(v0 + sr) * 1024 + kb + sby, da + w * 1024);
    gl16((const char*)bp + (size_t)(j0 + sr) * 1024 + kb + sby, db + w * 1024);
  };
  stage(0);
  __syncthreads();
  for (int c = 0; c < 24; ++c) {
    const char* ca = sA + (c & 1) * 8192;
    const char* cb = sB + (c & 1) * 8192;
    if (c < 23) stage(c + 1);
    GEMM_MFMA(ca, cb)
    __syncthreads();
  }
#pragma unroll
  for (int n = 0; n < 2; ++n) {
    const int j = j0 + (wc << 5) + (n << 4) + lrow;
#pragma unroll
    for (int ri = 0; ri < 4; ++ri)
      g_proj[(size_t)(v0 + (wr << 4) + lk * 4 + ri) * 1024 + j] = acc[n][ri];
  }
}

// One RNN step. Single-pass chunks: each k=64 chunk stages {Ah|Al|Wh|Wl} once
// (32 KB) and runs all 12 MFMAs. 16 chunks, ring-2, counted vmcnt, 64 KB LDS
// -> 2 blocks/CU (m114 overlap preserved). Every operand staged exactly once.
__global__ void __launch_bounds__(512) step_k(const int* __restrict__ x_in,
                                              const int* __restrict__ x_len, int t) {
  __shared__ char ring[65536];   // 2 slots x {Ah 8K | Al 8K | Wh 8K | Wl 8K}
  __shared__ int toks[64];
  GEMM_PROLOG()
  const int b0 = (bid & 15) << 6, j0 = (bid >> 4) << 6;
  const u16* hinh = g_hh[t & 1];
  const u16* hinl = g_hl[t & 1];
  u16* houth = g_hh[(t + 1) & 1];
  u16* houtl = g_hl[(t + 1) & 1];

  if (tid < 64) toks[tid] = x_in[(b0 + tid) * Ss + t];
  __syncthreads();

  // x-projection gather: issued FIRST (oldest vmcnt entries -> drained by the
  // first counted wait, off the K-loop critical path), consumed in the tail.
  float pj[2][4];
#pragma unroll
  for (int n = 0; n < 2; ++n) {
    const int j = j0 + (wc << 5) + (n << 4) + lrow;
#pragma unroll
    for (int ri = 0; ri < 4; ++ri)
      pj[n][ri] = g_proj[(size_t)toks[(wr << 4) + lk * 4 + ri] * 1024 + j];
  }
  asm volatile("" ::: "memory");

  f32x4 acc[2];
  acc[0] = (f32x4){0.f, 0.f, 0.f, 0.f}; acc[1] = acc[0];

  if (t > 0) {
    auto stage = [&](int c) {
      char* sl = ring + (c & 1) * 32768;
      const int kb = c * 128;
      gl16((const char*)hinh + (size_t)(b0 + sr) * 2048 + kb + sby, sl + w * 1024);
      gl16((const char*)hinl + (size_t)(b0 + sr) * 2048 + kb + sby, sl + 8192 + w * 1024);
      gl16((const char*)t_hh + (size_t)(j0 + sr) * 2048 + kb + sby, sl + 16384 + w * 1024);
      gl16((const char*)t_hl + (size_t)(j0 + sr) * 2048 + kb + sby, sl + 24576 + w * 1024);
    };
    stage(0); stage(1);
    for (int c = 0; c < 16; ++c) {
      if (c < 15) asm volatile("s_waitcnt vmcnt(4)" ::: "memory");
      else        asm volatile("s_waitcnt vmcnt(0)" ::: "memory");
      __builtin_amdgcn_s_barrier();          // chunk c fully staged (all waves)
      __builtin_amdgcn_sched_barrier(0);     // rule #18
      const char* sl = ring + (c & 1) * 32768;
#pragma unroll
      for (int s = 0; s < 2; ++s) {
        short8 aH = *(const short8*)(sl + aoff[s]);
        short8 aL = *(const short8*)(sl + 8192 + aoff[s]);
#pragma unroll
        for (int n = 0; n < 2; ++n) {
          short8 bH = *(const short8*)(sl + 16384 + bboff[n][s]);
          short8 bL = *(const short8*)(sl + 24576 + bboff[n][s]);
          acc[n] = __builtin_amdgcn_mfma_f32_16x16x32_bf16(aH, bH, acc[n], 0, 0, 0);
          acc[n] = __builtin_amdgcn_mfma_f32_16x16x32_bf16(aL, bH, acc[n], 0, 0, 0);
          acc[n] = __builtin_amdgcn_mfma_f32_16x16x32_bf16(aH, bL, acc[n], 0, 0, 0);
        }
      }
      __builtin_amdgcn_s_barrier();          // slot free before restage
      if (c + 2 < 16) stage(c + 2);
    }
  }

  // tail: tanh, split-store h, y-capture
#pragma unroll
  for (int n = 0; n < 2; ++n) {
    const int j = j0 + (wc << 5) + (n << 4) + lrow;
#pragma unroll
    for (int ri = 0; ri < 4; ++ri) {
      const int brow = b0 + (wr << 4) + lk * 4 + ri;
      const float v = tanhf(acc[n][ri] + pj[n][ri]);
      const unsigned hi = f2bf(v);
      const unsigned lo = f2bf(v - bf2f(hi));
      const size_t off = (size_t)brow * 1024 + j;
      houth[off] = (u16)hi;
      houtl[off] = (u16)lo;
      if (x_len[brow] == t + 1) { g_yh[off] = (u16)hi; g_yl[off] = (u16)lo; }
    }
  }
}

// MLP (unchanged from r12, green)
__global__ void __launch_bounds__(512) mlp_k(const float* __restrict__ bias,
                                             float* __restrict__ out, int mode) {
  __shared__ char sA[16384];
  __shared__ char sB[16384];
  GEMM_PROLOG()
  const int b0 = (bid & 15) << 6, j0 = (bid >> 4) << 6;
  const u16* ah = mode ? g_zh : g_yh;
  const u16* al = mode ? g_zl : g_yl;
  const u16* bh = mode ? t_2h : t_1h;
  const u16* bl = mode ? t_2l : t_1l;

  f32x4 acc[2];
#pragma unroll
  for (int n = 0; n < 2; ++n) {
    const float bs = bias[j0 + (wc << 5) + (n << 4) + lrow];
#pragma unroll
    for (int ri = 0; ri < 4; ++ri) acc[n][ri] = bs;
  }

  auto stage = [&](int c) {
    char* da = sA + (c & 1) * 8192;
    char* db = sB + (c & 1) * 8192;
    const u16* ap = (c >= 16 && c < 32) ? al : ah;
    const u16* bp = (c < 32) ? bh : bl;
    const int kb = (c & 15) * 128;
    gl16((const char*)ap + (size_t)(b0 + sr) * 2048 + kb + sby, da + w * 1024);
    gl16((const char*)bp + (size_t)(j0 + sr) * 2048 + kb + sby, db + w * 1024);
  };
  stage(0);
  __syncthreads();
  for (int c = 0; c < 48; ++c) {
    const char* ca = sA + (c & 1) * 8192;
    const char* cb = sB + (c & 1) * 8192;
    if (c < 47) stage(c + 1);
    GEMM_MFMA(ca, cb)
    __syncthreads();
  }

#pragma unroll
  for (int n = 0; n < 2; ++n) {
    const int j = j0 + (wc << 5) + (n << 4) + lrow;
#pragma unroll
    for (int ri = 0; ri < 4; ++ri) {
      const int brow = b0 + (wr << 4) + lk * 4 + ri;
      if (mode == 0) {
        const float v = fmaxf(acc[n][ri], 0.f);
        const unsigned hi = f2bf(v);
        const unsigned lo = f2bf(v - bf2f(hi));
        const size_t off = (size_t)brow * 1024 + j;
        g_zh[off] = (u16)hi;
        g_zl[off] = (u16)lo;
      } else {
        out[(size_t)brow * 512 + j] = acc[n][ri];
      }
    }
  }
}

extern "C" void kernel_launch(void* const* d_in, const int* in_sizes, int n_in,
                              void* d_out, int out_size, void* d_ws, size_t ws_size,
                              hipStream_t stream) {
  const int*   x_in  = (const int*)d_in[0];
  const int*   x_len = (const int*)d_in[1];
  const float* emb = (const float*)d_in[2];
  const float* Wih = (const float*)d_in[3];
  const float* Whh = (const float*)d_in[4];
  const float* bih = (const float*)d_in[5];
  const float* bhh = (const float*)d_in[6];
  const float* W1  = (const float*)d_in[7];
  const float* b1  = (const float*)d_in[8];
  const float* W2  = (const float*)d_in[9];
  const float* b2  = (const float*)d_in[10];
  float* out = (float*)d_out;

  cvt_split<<<dim3(4096), dim3(256), 0, stream>>>(emb, 0, Vn * En);
  cvt_split<<<dim3(1024), dim3(256), 0, stream>>>(Wih, 1, Hn * En);
  cvt_split<<<dim3(2048), dim3(256), 0, stream>>>(Whh, 2, Hn * Hn);
  cvt_split<<<dim3(2048), dim3(256), 0, stream>>>(W1, 3, Hn * Hn);
  cvt_split<<<dim3(1024), dim3(256), 0, stream>>>(W2, 4, Cn * Hn);

  proj_k<<<dim3(8000), dim3(512), 0, stream>>>(bih, bhh);

  for (int t = 0; t < Ss; ++t)
    step_k<<<dim3(256), dim3(512), 0, stream>>>(x_in, x_len, t);

  mlp_k<<<dim3(256), dim3(512), 0, stream>>>(b1, nullptr, 0);
  mlp_k<<<dim3(128), dim3(512), 0, stream>>>(b2, out, 1);
}

// Round 15
// 1736.448 us; speedup vs baseline: 4.2536x; 1.1473x over previous
//
#include <hip/hip_runtime.h>

typedef unsigned short u16;
constexpr int Ss = 128, Hn = 1024, En = 512, Cn = 512, Vn = 32000;
constexpr size_t PL = 1024u * 1024u;

using short8 = __attribute__((ext_vector_type(8))) short;
using f32x4  = __attribute__((ext_vector_type(4))) float;

// ---- static device scratch (all planes rewritten in-launch before read) ----
__device__ __align__(1024) u16 g_hh[2][PL];   // h ping-pong, hi
__device__ __align__(1024) u16 g_hl[2][PL];   // h ping-pong, lo
__device__ __align__(1024) u16 g_yh[PL], g_yl[PL];
__device__ __align__(1024) u16 g_zh[PL], g_zl[PL];
__device__ __align__(1024) float g_proj[(size_t)Vn * Hn];  // emb@Wih^T + bih + bhh
// bf16 hi/lo split tables (recomputed every launch; deterministic)
__device__ __align__(1024) u16 t_eh[(size_t)Vn * En], t_el[(size_t)Vn * En];
__device__ __align__(1024) u16 t_xh[(size_t)Hn * En], t_xl[(size_t)Hn * En];  // Wih
__device__ __align__(1024) u16 t_hh[(size_t)Hn * Hn], t_hl[(size_t)Hn * Hn];  // Whh
__device__ __align__(1024) u16 t_1h[(size_t)Hn * Hn], t_1l[(size_t)Hn * Hn];  // W1
__device__ __align__(1024) u16 t_2h[(size_t)Cn * Hn], t_2l[(size_t)Cn * Hn];  // W2

__device__ __forceinline__ void gl16(const void* g, void* l) {
  __builtin_amdgcn_global_load_lds((const __attribute__((address_space(1))) void*)g,
                                   (__attribute__((address_space(3))) void*)l, 16, 0, 0);
}
__device__ __forceinline__ unsigned f2bf(float f) {
  unsigned u = __float_as_uint(f);
  return (u + 0x7fffu + ((u >> 16) & 1u)) >> 16;
}
__device__ __forceinline__ float bf2f(unsigned u) { return __uint_as_float(u << 16); }

__global__ void cvt_split(const float* __restrict__ src, int which, int n) {
  u16 *hi, *lo;
  switch (which) {
    case 0: hi = t_eh; lo = t_el; break;
    case 1: hi = t_xh; lo = t_xl; break;
    case 2: hi = t_hh; lo = t_hl; break;
    case 3: hi = t_1h; lo = t_1l; break;
    default: hi = t_2h; lo = t_2l; break;
  }
  for (int i = blockIdx.x * blockDim.x + threadIdx.x; i < n; i += gridDim.x * blockDim.x) {
    const float v = src[i];
    const unsigned h = f2bf(v);
    hi[i] = (u16)h;
    lo[i] = (u16)f2bf(v - bf2f(h));
  }
}

// Shared GEMM-tile prolog (r12/r14-proven: 64x64 tile, 8 waves 4x2, m89 frags,
// XOR-swizzled LDS via gl16).
#define GEMM_PROLOG_NOBID()                                                    \
  const int tid = threadIdx.x;                                                 \
  const int w = tid >> 6, l = tid & 63;                                        \
  const int wr = w & 3, wc = w >> 2;                                           \
  const int lrow = l & 15, lk = l >> 4;                                        \
  const int sr = tid >> 3, p = tid & 7;                                        \
  const int sby = ((p ^ (sr & 7)) << 4);                                       \
  const int arow = (wr << 4) + lrow;                                           \
  int aoff[2], bboff[2][2];                                                    \
  _Pragma("unroll") for (int s = 0; s < 2; ++s)                                \
      aoff[s] = arow * 128 + ((s * 64 + lk * 16) ^ ((arow & 7) << 4));         \
  _Pragma("unroll") for (int n = 0; n < 2; ++n) {                              \
    const int jl = (wc << 5) + (n << 4) + lrow;                                \
    _Pragma("unroll") for (int s = 0; s < 2; ++s)                              \
        bboff[n][s] = jl * 128 + ((s * 64 + lk * 16) ^ ((jl & 7) << 4));       \
  }
#define GEMM_PROLOG() const int bid = blockIdx.x; GEMM_PROLOG_NOBID()

#define GEMM_MFMA(ca, cb)                                                      \
  _Pragma("unroll") for (int s = 0; s < 2; ++s) {                              \
    short8 a = *(const short8*)((ca) + aoff[s]);                               \
    _Pragma("unroll") for (int n = 0; n < 2; ++n) {                            \
      short8 b = *(const short8*)((cb) + bboff[n][s]);                         \
      acc[n] = __builtin_amdgcn_mfma_f32_16x16x32_bf16(a, b, acc[n], 0, 0, 0); \
    }                                                                          \
  }

// proj[v][j] = emb[v] @ Wih^T + bih[j] + bhh[j]
// r15: single-pass chunks {Eh|El|Xh|Xl}, 8 chunks, ring-2; v-major bid remap
// (same-v blocks -> 2 XCDs, 4x less emb L2 replication).
__global__ void __launch_bounds__(512) proj_k(const float* __restrict__ bih,
                                              const float* __restrict__ bhh) {
  __shared__ char ring[65536];   // 2 slots x {Eh 8K | El 8K | Xh 8K | Xl 8K}
  GEMM_PROLOG()
  const int v0 = (bid % 500) << 6;
  const int j0 = (bid / 500) << 6;

  f32x4 acc[2];
#pragma unroll
  for (int n = 0; n < 2; ++n) {
    const float bs = bih[j0 + (wc << 5) + (n << 4) + lrow] +
                     bhh[j0 + (wc << 5) + (n << 4) + lrow];
#pragma unroll
    for (int ri = 0; ri < 4; ++ri) acc[n][ri] = bs;
  }

  auto stage = [&](int c) {
    char* sl = ring + (c & 1) * 32768;
    const int kb = c * 128;
    gl16((const char*)t_eh + (size_t)(v0 + sr) * 1024 + kb + sby, sl + w * 1024);
    gl16((const char*)t_el + (size_t)(v0 + sr) * 1024 + kb + sby, sl + 8192 + w * 1024);
    gl16((const char*)t_xh + (size_t)(j0 + sr) * 1024 + kb + sby, sl + 16384 + w * 1024);
    gl16((const char*)t_xl + (size_t)(j0 + sr) * 1024 + kb + sby, sl + 24576 + w * 1024);
  };
  stage(0); stage(1);
  for (int c = 0; c < 8; ++c) {
    if (c < 7) asm volatile("s_waitcnt vmcnt(4)" ::: "memory");
    else       asm volatile("s_waitcnt vmcnt(0)" ::: "memory");
    __builtin_amdgcn_s_barrier();
    __builtin_amdgcn_sched_barrier(0);
    const char* sl = ring + (c & 1) * 32768;
#pragma unroll
    for (int s = 0; s < 2; ++s) {
      short8 aH = *(const short8*)(sl + aoff[s]);
      short8 aL = *(const short8*)(sl + 8192 + aoff[s]);
#pragma unroll
      for (int n = 0; n < 2; ++n) {
        short8 bH = *(const short8*)(sl + 16384 + bboff[n][s]);
        short8 bL = *(const short8*)(sl + 24576 + bboff[n][s]);
        acc[n] = __builtin_amdgcn_mfma_f32_16x16x32_bf16(aH, bH, acc[n], 0, 0, 0);
        acc[n] = __builtin_amdgcn_mfma_f32_16x16x32_bf16(aL, bH, acc[n], 0, 0, 0);
        acc[n] = __builtin_amdgcn_mfma_f32_16x16x32_bf16(aH, bL, acc[n], 0, 0, 0);
      }
    }
    __builtin_amdgcn_s_barrier();
    if (c + 2 < 8) stage(c + 2);
  }
#pragma unroll
  for (int n = 0; n < 2; ++n) {
    const int j = j0 + (wc << 5) + (n << 4) + lrow;
#pragma unroll
    for (int ri = 0; ri < 4; ++ri)
      g_proj[(size_t)(v0 + (wr << 4) + lk * 4 + ri) * 1024 + j] = acc[n][ri];
  }
}

// One RNN step. r14 single-pass chunks; r15: ring-4 (128 KB), prefetch dist 3,
// counted vmcnt(8) -> loads get ~3 chunks of latency cover (1 block/CU anyway).
__global__ void __launch_bounds__(512) step_k(const int* __restrict__ x_in,
                                              const int* __restrict__ x_len, int t) {
  extern __shared__ char ring[];   // 4 slots x {Ah 8K | Al 8K | Wh 8K | Wl 8K}
  __shared__ int toks[64];
  GEMM_PROLOG()
  const int b0 = (bid & 15) << 6, j0 = (bid >> 4) << 6;
  const u16* hinh = g_hh[t & 1];
  const u16* hinl = g_hl[t & 1];
  u16* houth = g_hh[(t + 1) & 1];
  u16* houtl = g_hl[(t + 1) & 1];

  if (tid < 64) toks[tid] = x_in[(b0 + tid) * Ss + t];
  __syncthreads();

  // x-projection gather: issued FIRST (oldest vmcnt entries, drained by the
  // first counted wait), consumed in the tail.
  float pj[2][4];
#pragma unroll
  for (int n = 0; n < 2; ++n) {
    const int j = j0 + (wc << 5) + (n << 4) + lrow;
#pragma unroll
    for (int ri = 0; ri < 4; ++ri)
      pj[n][ri] = g_proj[(size_t)toks[(wr << 4) + lk * 4 + ri] * 1024 + j];
  }
  asm volatile("" ::: "memory");

  f32x4 acc[2];
  acc[0] = (f32x4){0.f, 0.f, 0.f, 0.f}; acc[1] = acc[0];

  if (t > 0) {
    auto stage = [&](int c) {
      char* sl = ring + (c & 3) * 32768;
      const int kb = c * 128;
      gl16((const char*)hinh + (size_t)(b0 + sr) * 2048 + kb + sby, sl + w * 1024);
      gl16((const char*)hinl + (size_t)(b0 + sr) * 2048 + kb + sby, sl + 8192 + w * 1024);
      gl16((const char*)t_hh + (size_t)(j0 + sr) * 2048 + kb + sby, sl + 16384 + w * 1024);
      gl16((const char*)t_hl + (size_t)(j0 + sr) * 2048 + kb + sby, sl + 24576 + w * 1024);
    };
    stage(0); stage(1); stage(2);
    for (int c = 0; c < 16; ++c) {
      const int left = 15 - c;                // chunks still ahead
      if (left >= 3)      asm volatile("s_waitcnt vmcnt(8)" ::: "memory");
      else if (left == 2) asm volatile("s_waitcnt vmcnt(8)" ::: "memory");
      else if (left == 1) asm volatile("s_waitcnt vmcnt(4)" ::: "memory");
      else                asm volatile("s_waitcnt vmcnt(0)" ::: "memory");
      __builtin_amdgcn_s_barrier();          // chunk c fully staged (all waves)
      __builtin_amdgcn_sched_barrier(0);     // rule #18
      const char* sl = ring + (c & 3) * 32768;
#pragma unroll
      for (int s = 0; s < 2; ++s) {
        short8 aH = *(const short8*)(sl + aoff[s]);
        short8 aL = *(const short8*)(sl + 8192 + aoff[s]);
#pragma unroll
        for (int n = 0; n < 2; ++n) {
          short8 bH = *(const short8*)(sl + 16384 + bboff[n][s]);
          short8 bL = *(const short8*)(sl + 24576 + bboff[n][s]);
          acc[n] = __builtin_amdgcn_mfma_f32_16x16x32_bf16(aH, bH, acc[n], 0, 0, 0);
          acc[n] = __builtin_amdgcn_mfma_f32_16x16x32_bf16(aL, bH, acc[n], 0, 0, 0);
          acc[n] = __builtin_amdgcn_mfma_f32_16x16x32_bf16(aH, bL, acc[n], 0, 0, 0);
        }
      }
      __builtin_amdgcn_s_barrier();          // slot (c+3)&3 reads done (chunk c-1)
      if (c + 3 < 16) stage(c + 3);
    }
  }

  // tail: tanh, split-store h, y-capture
#pragma unroll
  for (int n = 0; n < 2; ++n) {
    const int j = j0 + (wc << 5) + (n << 4) + lrow;
#pragma unroll
    for (int ri = 0; ri < 4; ++ri) {
      const int brow = b0 + (wr << 4) + lk * 4 + ri;
      const float v = tanhf(acc[n][ri] + pj[n][ri]);
      const unsigned hi = f2bf(v);
      const unsigned lo = f2bf(v - bf2f(hi));
      const size_t off = (size_t)brow * 1024 + j;
      houth[off] = (u16)hi;
      houtl[off] = (u16)lo;
      if (x_len[brow] == t + 1) { g_yh[off] = (u16)hi; g_yl[off] = (u16)lo; }
    }
  }
}

// MLP (unchanged from r12, green)
__global__ void __launch_bounds__(512) mlp_k(const float* __restrict__ bias,
                                             float* __restrict__ out, int mode) {
  __shared__ char sA[16384];
  __shared__ char sB[16384];
  GEMM_PROLOG()
  const int b0 = (bid & 15) << 6, j0 = (bid >> 4) << 6;
  const u16* ah = mode ? g_zh : g_yh;
  const u16* al = mode ? g_zl : g_yl;
  const u16* bh = mode ? t_2h : t_1h;
  const u16* bl = mode ? t_2l : t_1l;

  f32x4 acc[2];
#pragma unroll
  for (int n = 0; n < 2; ++n) {
    const float bs = bias[j0 + (wc << 5) + (n << 4) + lrow];
#pragma unroll
    for (int ri = 0; ri < 4; ++ri) acc[n][ri] = bs;
  }

  auto stage = [&](int c) {
    char* da = sA + (c & 1) * 8192;
    char* db = sB + (c & 1) * 8192;
    const u16* ap = (c >= 16 && c < 32) ? al : ah;
    const u16* bp = (c < 32) ? bh : bl;
    const int kb = (c & 15) * 128;
    gl16((const char*)ap + (size_t)(b0 + sr) * 2048 + kb + sby, da + w * 1024);
    gl16((const char*)bp + (size_t)(j0 + sr) * 2048 + kb + sby, db + w * 1024);
  };
  stage(0);
  __syncthreads();
  for (int c = 0; c < 48; ++c) {
    const char* ca = sA + (c & 1) * 8192;
    const char* cb = sB + (c & 1) * 8192;
    if (c < 47) stage(c + 1);
    GEMM_MFMA(ca, cb)
    __syncthreads();
  }

#pragma unroll
  for (int n = 0; n < 2; ++n) {
    const int j = j0 + (wc << 5) + (n << 4) + lrow;
#pragma unroll
    for (int ri = 0; ri < 4; ++ri) {
      const int brow = b0 + (wr << 4) + lk * 4 + ri;
      if (mode == 0) {
        const float v = fmaxf(acc[n][ri], 0.f);
        const unsigned hi = f2bf(v);
        const unsigned lo = f2bf(v - bf2f(hi));
        const size_t off = (size_t)brow * 1024 + j;
        g_zh[off] = (u16)hi;
        g_zl[off] = (u16)lo;
      } else {
        out[(size_t)brow * 512 + j] = acc[n][ri];
      }
    }
  }
}

extern "C" void kernel_launch(void* const* d_in, const int* in_sizes, int n_in,
                              void* d_out, int out_size, void* d_ws, size_t ws_size,
                              hipStream_t stream) {
  const int*   x_in  = (const int*)d_in[0];
  const int*   x_len = (const int*)d_in[1];
  const float* emb = (const float*)d_in[2];
  const float* Wih = (const float*)d_in[3];
  const float* Whh = (const float*)d_in[4];
  const float* bih = (const float*)d_in[5];
  const float* bhh = (const float*)d_in[6];
  const float* W1  = (const float*)d_in[7];
  const float* b1  = (const float*)d_in[8];
  const float* W2  = (const float*)d_in[9];
  const float* b2  = (const float*)d_in[10];
  float* out = (float*)d_out;

  (void)hipFuncSetAttribute((const void*)step_k,
                            hipFuncAttributeMaxDynamicSharedMemorySize, 131072);

  cvt_split<<<dim3(4096), dim3(256), 0, stream>>>(emb, 0, Vn * En);
  cvt_split<<<dim3(1024), dim3(256), 0, stream>>>(Wih, 1, Hn * En);
  cvt_split<<<dim3(2048), dim3(256), 0, stream>>>(Whh, 2, Hn * Hn);
  cvt_split<<<dim3(2048), dim3(256), 0, stream>>>(W1, 3, Hn * Hn);
  cvt_split<<<dim3(1024), dim3(256), 0, stream>>>(W2, 4, Cn * Hn);

  proj_k<<<dim3(8000), dim3(512), 0, stream>>>(bih, bhh);

  for (int t = 0; t < Ss; ++t)
    step_k<<<dim3(256), dim3(512), 131072, stream>>>(x_in, x_len, t);

  mlp_k<<<dim3(256), dim3(512), 0, stream>>>(b1, nullptr, 0);
  mlp_k<<<dim3(128), dim3(512), 0, stream>>>(b2, out, 1);
}

// Round 16
// 1731.332 us; speedup vs baseline: 4.2662x; 1.0030x over previous
//
#include <hip/hip_runtime.h>

typedef unsigned short u16;
constexpr int Ss = 128, Hn = 1024, En = 512, Cn = 512, Vn = 32000;
constexpr size_t PL = 1024u * 1024u;

using short8 = __attribute__((ext_vector_type(8))) short;
using f32x4  = __attribute__((ext_vector_type(4))) float;

// ---- static device scratch (all planes rewritten in-launch before read) ----
__device__ __align__(1024) u16 g_hh[2][PL];   // h ping-pong, hi
__device__ __align__(1024) u16 g_hl[2][PL];   // h ping-pong, lo
__device__ __align__(1024) u16 g_yh[PL], g_yl[PL];
__device__ __align__(1024) u16 g_zh[PL], g_zl[PL];
__device__ __align__(1024) float g_proj[(size_t)Vn * Hn];  // emb@Wih^T + bih + bhh
// bf16 hi/lo split tables (recomputed every launch; deterministic)
__device__ __align__(1024) u16 t_eh[(size_t)Vn * En], t_el[(size_t)Vn * En];
__device__ __align__(1024) u16 t_xh[(size_t)Hn * En], t_xl[(size_t)Hn * En];  // Wih
__device__ __align__(1024) u16 t_hh[(size_t)Hn * Hn], t_hl[(size_t)Hn * Hn];  // Whh
__device__ __align__(1024) u16 t_1h[(size_t)Hn * Hn], t_1l[(size_t)Hn * Hn];  // W1
__device__ __align__(1024) u16 t_2h[(size_t)Cn * Hn], t_2l[(size_t)Cn * Hn];  // W2

__device__ __forceinline__ void gl16(const void* g, void* l) {
  __builtin_amdgcn_global_load_lds((const __attribute__((address_space(1))) void*)g,
                                   (__attribute__((address_space(3))) void*)l, 16, 0, 0);
}
__device__ __forceinline__ unsigned f2bf(float f) {
  unsigned u = __float_as_uint(f);
  return (u + 0x7fffu + ((u >> 16) & 1u)) >> 16;
}
__device__ __forceinline__ float bf2f(unsigned u) { return __uint_as_float(u << 16); }

__global__ void cvt_split(const float* __restrict__ src, int which, int n) {
  u16 *hi, *lo;
  switch (which) {
    case 0: hi = t_eh; lo = t_el; break;
    case 1: hi = t_xh; lo = t_xl; break;
    case 2: hi = t_hh; lo = t_hl; break;
    case 3: hi = t_1h; lo = t_1l; break;
    default: hi = t_2h; lo = t_2l; break;
  }
  for (int i = blockIdx.x * blockDim.x + threadIdx.x; i < n; i += gridDim.x * blockDim.x) {
    const float v = src[i];
    const unsigned h = f2bf(v);
    hi[i] = (u16)h;
    lo[i] = (u16)f2bf(v - bf2f(h));
  }
}

// Shared GEMM-tile prolog (r12/r14-proven: 64x64 tile, 8 waves 4x2, m89 frags,
// XOR-swizzled LDS via gl16).
#define GEMM_PROLOG_NOBID()                                                    \
  const int tid = threadIdx.x;                                                 \
  const int w = tid >> 6, l = tid & 63;                                        \
  const int wr = w & 3, wc = w >> 2;                                           \
  const int lrow = l & 15, lk = l >> 4;                                        \
  const int sr = tid >> 3, p = tid & 7;                                        \
  const int sby = ((p ^ (sr & 7)) << 4);                                       \
  const int arow = (wr << 4) + lrow;                                           \
  int aoff[2], bboff[2][2];                                                    \
  _Pragma("unroll") for (int s = 0; s < 2; ++s)                                \
      aoff[s] = arow * 128 + ((s * 64 + lk * 16) ^ ((arow & 7) << 4));         \
  _Pragma("unroll") for (int n = 0; n < 2; ++n) {                              \
    const int jl = (wc << 5) + (n << 4) + lrow;                                \
    _Pragma("unroll") for (int s = 0; s < 2; ++s)                              \
        bboff[n][s] = jl * 128 + ((s * 64 + lk * 16) ^ ((jl & 7) << 4));       \
  }
#define GEMM_PROLOG() const int bid = blockIdx.x; GEMM_PROLOG_NOBID()

#define GEMM_MFMA(ca, cb)                                                      \
  _Pragma("unroll") for (int s = 0; s < 2; ++s) {                              \
    short8 a = *(const short8*)((ca) + aoff[s]);                               \
    _Pragma("unroll") for (int n = 0; n < 2; ++n) {                            \
      short8 b = *(const short8*)((cb) + bboff[n][s]);                         \
      acc[n] = __builtin_amdgcn_mfma_f32_16x16x32_bf16(a, b, acc[n], 0, 0, 0); \
    }                                                                          \
  }

// proj[v][j] = emb[v] @ Wih^T + bih[j] + bhh[j]   (unchanged from r15, green:
// 2 blocks/CU -> co-resident overlap, 3.9 TB/s)
__global__ void __launch_bounds__(512) proj_k(const float* __restrict__ bih,
                                              const float* __restrict__ bhh) {
  __shared__ char ring[65536];   // 2 slots x {Eh 8K | El 8K | Xh 8K | Xl 8K}
  GEMM_PROLOG()
  const int v0 = (bid % 500) << 6;
  const int j0 = (bid / 500) << 6;

  f32x4 acc[2];
#pragma unroll
  for (int n = 0; n < 2; ++n) {
    const float bs = bih[j0 + (wc << 5) + (n << 4) + lrow] +
                     bhh[j0 + (wc << 5) + (n << 4) + lrow];
#pragma unroll
    for (int ri = 0; ri < 4; ++ri) acc[n][ri] = bs;
  }

  auto stage = [&](int c) {
    char* sl = ring + (c & 1) * 32768;
    const int kb = c * 128;
    gl16((const char*)t_eh + (size_t)(v0 + sr) * 1024 + kb + sby, sl + w * 1024);
    gl16((const char*)t_el + (size_t)(v0 + sr) * 1024 + kb + sby, sl + 8192 + w * 1024);
    gl16((const char*)t_xh + (size_t)(j0 + sr) * 1024 + kb + sby, sl + 16384 + w * 1024);
    gl16((const char*)t_xl + (size_t)(j0 + sr) * 1024 + kb + sby, sl + 24576 + w * 1024);
  };
  stage(0); stage(1);
  for (int c = 0; c < 8; ++c) {
    if (c < 7) asm volatile("s_waitcnt vmcnt(4)" ::: "memory");
    else       asm volatile("s_waitcnt vmcnt(0)" ::: "memory");
    __builtin_amdgcn_s_barrier();
    __builtin_amdgcn_sched_barrier(0);
    const char* sl = ring + (c & 1) * 32768;
#pragma unroll
    for (int s = 0; s < 2; ++s) {
      short8 aH = *(const short8*)(sl + aoff[s]);
      short8 aL = *(const short8*)(sl + 8192 + aoff[s]);
#pragma unroll
      for (int n = 0; n < 2; ++n) {
        short8 bH = *(const short8*)(sl + 16384 + bboff[n][s]);
        short8 bL = *(const short8*)(sl + 24576 + bboff[n][s]);
        acc[n] = __builtin_amdgcn_mfma_f32_16x16x32_bf16(aH, bH, acc[n], 0, 0, 0);
        acc[n] = __builtin_amdgcn_mfma_f32_16x16x32_bf16(aL, bH, acc[n], 0, 0, 0);
        acc[n] = __builtin_amdgcn_mfma_f32_16x16x32_bf16(aH, bL, acc[n], 0, 0, 0);
      }
    }
    __builtin_amdgcn_s_barrier();
    if (c + 2 < 8) stage(c + 2);
  }
#pragma unroll
  for (int n = 0; n < 2; ++n) {
    const int j = j0 + (wc << 5) + (n << 4) + lrow;
#pragma unroll
    for (int ri = 0; ri < 4; ++ri)
      g_proj[(size_t)(v0 + (wr << 4) + lk * 4 + ri) * 1024 + j] = acc[n][ri];
  }
}

// One RNN step. r16: ONE barrier per chunk (post-MFMA barrier removed — slot
// (c+3)&3's prior reads are provably complete once any wave passes iter-c's
// barrier), stage issued right after the barrier -> 3 full chunks of cover.
__global__ void __launch_bounds__(512) step_k(const int* __restrict__ x_in,
                                              const int* __restrict__ x_len, int t) {
  extern __shared__ char ring[];   // 4 slots x {Ah 8K | Al 8K | Wh 8K | Wl 8K}
  __shared__ int toks[64];
  GEMM_PROLOG()
  const int b0 = (bid & 15) << 6, j0 = (bid >> 4) << 6;
  const u16* hinh = g_hh[t & 1];
  const u16* hinl = g_hl[t & 1];
  u16* houth = g_hh[(t + 1) & 1];
  u16* houtl = g_hl[(t + 1) & 1];

  if (tid < 64) toks[tid] = x_in[(b0 + tid) * Ss + t];
  __syncthreads();

  // x-projection gather: issued FIRST (oldest vmcnt entries, drained by the
  // first counted wait), consumed in the tail.
  float pj[2][4];
#pragma unroll
  for (int n = 0; n < 2; ++n) {
    const int j = j0 + (wc << 5) + (n << 4) + lrow;
#pragma unroll
    for (int ri = 0; ri < 4; ++ri)
      pj[n][ri] = g_proj[(size_t)toks[(wr << 4) + lk * 4 + ri] * 1024 + j];
  }
  asm volatile("" ::: "memory");

  f32x4 acc[2];
  acc[0] = (f32x4){0.f, 0.f, 0.f, 0.f}; acc[1] = acc[0];

  if (t > 0) {
    auto stage = [&](int c) {
      char* sl = ring + (c & 3) * 32768;
      const int kb = c * 128;
      gl16((const char*)hinh + (size_t)(b0 + sr) * 2048 + kb + sby, sl + w * 1024);
      gl16((const char*)hinl + (size_t)(b0 + sr) * 2048 + kb + sby, sl + 8192 + w * 1024);
      gl16((const char*)t_hh + (size_t)(j0 + sr) * 2048 + kb + sby, sl + 16384 + w * 1024);
      gl16((const char*)t_hl + (size_t)(j0 + sr) * 2048 + kb + sby, sl + 24576 + w * 1024);
    };
    stage(0); stage(1); stage(2);
    for (int c = 0; c < 16; ++c) {
      const int left = 15 - c;                // chunks still ahead
      if (left >= 2)      asm volatile("s_waitcnt vmcnt(8)" ::: "memory");
      else if (left == 1) asm volatile("s_waitcnt vmcnt(4)" ::: "memory");
      else                asm volatile("s_waitcnt vmcnt(0)" ::: "memory");
      __builtin_amdgcn_s_barrier();          // chunk c staged by ALL waves;
                                             // also: all slot-(c-1) reads done
      __builtin_amdgcn_sched_barrier(0);     // rule #18
      if (c + 3 < 16) stage(c + 3);          // overwrite slot (c-1)&3: safe here
      const char* sl = ring + (c & 3) * 32768;
#pragma unroll
      for (int s = 0; s < 2; ++s) {
        short8 aH = *(const short8*)(sl + aoff[s]);
        short8 aL = *(const short8*)(sl + 8192 + aoff[s]);
#pragma unroll
        for (int n = 0; n < 2; ++n) {
          short8 bH = *(const short8*)(sl + 16384 + bboff[n][s]);
          short8 bL = *(const short8*)(sl + 24576 + bboff[n][s]);
          acc[n] = __builtin_amdgcn_mfma_f32_16x16x32_bf16(aH, bH, acc[n], 0, 0, 0);
          acc[n] = __builtin_amdgcn_mfma_f32_16x16x32_bf16(aL, bH, acc[n], 0, 0, 0);
          acc[n] = __builtin_amdgcn_mfma_f32_16x16x32_bf16(aH, bL, acc[n], 0, 0, 0);
        }
      }
      // no second barrier (see header comment)
    }
  }

  // tail: tanh, split-store h, y-capture
#pragma unroll
  for (int n = 0; n < 2; ++n) {
    const int j = j0 + (wc << 5) + (n << 4) + lrow;
#pragma unroll
    for (int ri = 0; ri < 4; ++ri) {
      const int brow = b0 + (wr << 4) + lk * 4 + ri;
      const float v = tanhf(acc[n][ri] + pj[n][ri]);
      const unsigned hi = f2bf(v);
      const unsigned lo = f2bf(v - bf2f(hi));
      const size_t off = (size_t)brow * 1024 + j;
      houth[off] = (u16)hi;
      houtl[off] = (u16)lo;
      if (x_len[brow] == t + 1) { g_yh[off] = (u16)hi; g_yl[off] = (u16)lo; }
    }
  }
}

// MLP (unchanged from r12, green)
__global__ void __launch_bounds__(512) mlp_k(const float* __restrict__ bias,
                                             float* __restrict__ out, int mode) {
  __shared__ char sA[16384];
  __shared__ char sB[16384];
  GEMM_PROLOG()
  const int b0 = (bid & 15) << 6, j0 = (bid >> 4) << 6;
  const u16* ah = mode ? g_zh : g_yh;
  const u16* al = mode ? g_zl : g_yl;
  const u16* bh = mode ? t_2h : t_1h;
  const u16* bl = mode ? t_2l : t_1l;

  f32x4 acc[2];
#pragma unroll
  for (int n = 0; n < 2; ++n) {
    const float bs = bias[j0 + (wc << 5) + (n << 4) + lrow];
#pragma unroll
    for (int ri = 0; ri < 4; ++ri) acc[n][ri] = bs;
  }

  auto stage = [&](int c) {
    char* da = sA + (c & 1) * 8192;
    char* db = sB + (c & 1) * 8192;
    const u16* ap = (c >= 16 && c < 32) ? al : ah;
    const u16* bp = (c < 32) ? bh : bl;
    const int kb = (c & 15) * 128;
    gl16((const char*)ap + (size_t)(b0 + sr) * 2048 + kb + sby, da + w * 1024);
    gl16((const char*)bp + (size_t)(j0 + sr) * 2048 + kb + sby, db + w * 1024);
  };
  stage(0);
  __syncthreads();
  for (int c = 0; c < 48; ++c) {
    const char* ca = sA + (c & 1) * 8192;
    const char* cb = sB + (c & 1) * 8192;
    if (c < 47) stage(c + 1);
    GEMM_MFMA(ca, cb)
    __syncthreads();
  }

#pragma unroll
  for (int n = 0; n < 2; ++n) {
    const int j = j0 + (wc << 5) + (n << 4) + lrow;
#pragma unroll
    for (int ri = 0; ri < 4; ++ri) {
      const int brow = b0 + (wr << 4) + lk * 4 + ri;
      if (mode == 0) {
        const float v = fmaxf(acc[n][ri], 0.f);
        const unsigned hi = f2bf(v);
        const unsigned lo = f2bf(v - bf2f(hi));
        const size_t off = (size_t)brow * 1024 + j;
        g_zh[off] = (u16)hi;
        g_zl[off] = (u16)lo;
      } else {
        out[(size_t)brow * 512 + j] = acc[n][ri];
      }
    }
  }
}

extern "C" void kernel_launch(void* const* d_in, const int* in_sizes, int n_in,
                              void* d_out, int out_size, void* d_ws, size_t ws_size,
                              hipStream_t stream) {
  const int*   x_in  = (const int*)d_in[0];
  const int*   x_len = (const int*)d_in[1];
  const float* emb = (const float*)d_in[2];
  const float* Wih = (const float*)d_in[3];
  const float* Whh = (const float*)d_in[4];
  const float* bih = (const float*)d_in[5];
  const float* bhh = (const float*)d_in[6];
  const float* W1  = (const float*)d_in[7];
  const float* b1  = (const float*)d_in[8];
  const float* W2  = (const float*)d_in[9];
  const float* b2  = (const float*)d_in[10];
  float* out = (float*)d_out;

  (void)hipFuncSetAttribute((const void*)step_k,
                            hipFuncAttributeMaxDynamicSharedMemorySize, 131072);

  cvt_split<<<dim3(4096), dim3(256), 0, stream>>>(emb, 0, Vn * En);
  cvt_split<<<dim3(1024), dim3(256), 0, stream>>>(Wih, 1, Hn * En);
  cvt_split<<<dim3(2048), dim3(256), 0, stream>>>(Whh, 2, Hn * Hn);
  cvt_split<<<dim3(2048), dim3(256), 0, stream>>>(W1, 3, Hn * Hn);
  cvt_split<<<dim3(1024), dim3(256), 0, stream>>>(W2, 4, Cn * Hn);

  proj_k<<<dim3(8000), dim3(512), 0, stream>>>(bih, bhh);

  for (int t = 0; t < Ss; ++t)
    step_k<<<dim3(256), dim3(512), 131072, stream>>>(x_in, x_len, t);

  mlp_k<<<dim3(256), dim3(512), 0, stream>>>(b1, nullptr, 0);
  mlp_k<<<dim3(128), dim3(512), 0, stream>>>(b2, out, 1);
}